// Round 7
// baseline (241.998 us; speedup 1.0000x reference)
//
#include <hip/hip_runtime.h>
#include <hip/hip_bf16.h>

#define B_ 16
#define S_ 4096
#define D_ 64
#define H_ 8
#define NB_ 64          // n_buckets
#define M_ 64           // bucket_size
#define CHUNKS_ 512     // per batch = H_*NB_
#define LOG2E 1.4426950408889634f
#define LN2 0.6931471805599453f

#define QS_ 72          // K LDS row stride (shorts)
#define VTS_ 68         // V^T row stride (dwords)
#define PS_ 72          // O-transpose staging row stride (shorts)

typedef short short8 __attribute__((ext_vector_type(8)));
typedef short short4v __attribute__((ext_vector_type(4)));
typedef float floatx4 __attribute__((ext_vector_type(4)));

__device__ __forceinline__ float bf2f(unsigned short s) {
    return __uint_as_float(((unsigned int)s) << 16);
}
__device__ __forceinline__ unsigned pk2(float a, float b) {
    __hip_bfloat162 h = __float22bfloat162_rn(make_float2(a, b));
    return *(unsigned*)&h;
}
__device__ __forceinline__ unsigned short f2bf1(float x) {   // 1 VALU (RNE, same bits as manual round)
    return (unsigned short)pk2(x, x);
}
__device__ __forceinline__ uint4 pack8(float4 a, float4 b) {
    uint4 u;
    u.x = pk2(a.x, a.y); u.y = pk2(a.z, a.w);
    u.z = pk2(b.x, b.y); u.w = pk2(b.z, b.w);
    return u;
}
__device__ __forceinline__ short4v mk4(unsigned lo, unsigned hi) {
    uint2 t = make_uint2(lo, hi);
    return *(short4v*)&t;
}

// ---------------- K1: hashing ----------------
// 4 tokens/thread, argmax dim split into two halves of 16 so acc stays at
// 64 VGPRs (no spill). Per-(token,i) FMA chain is textually IDENTICAL to
// rounds 1-6 -> bit-identical rotated values. Argmax merged across halves
// with exact (v, idx) tie-break == numpy first-occurrence argmax.
__global__ void __launch_bounds__(256)
hash_kernel(const float* __restrict__ qk,
            const float* __restrict__ rot,
            int* __restrict__ bucket) {
    int bh = blockIdx.x >> 2;      // (b*H + h)
    int tc = blockIdx.x & 3;       // 1024-token chunk
    int h = bh & 7;
    int b = bh >> 3;

    __shared__ float rl[64 * 32];
    #pragma unroll
    for (int k = 0; k < 8; k++) {
        int e = k * 256 + threadIdx.x;
        rl[e] = rot[(e >> 5) * (H_ * 32) + h * 32 + (e & 31)];
    }
    __syncthreads();

    const int t0 = tc * 1024 + threadIdx.x;   // tokens t0 + 256*u, u=0..3
    const float4* qrow[4];
    #pragma unroll
    for (int u = 0; u < 4; u++)
        qrow[u] = (const float4*)(qk + ((size_t)(b * S_ + t0 + 256 * u)) * D_);

    float best[4] = {-3.4e38f, -3.4e38f, -3.4e38f, -3.4e38f};
    int bi[4] = {0, 0, 0, 0};

    for (int hh = 0; hh < 2; hh++) {
        float acc[4][16];
        #pragma unroll
        for (int u = 0; u < 4; u++)
            #pragma unroll
            for (int i = 0; i < 16; i++) acc[u][i] = 0.f;

        float4 nx0 = qrow[0][0], nx1 = qrow[1][0], nx2 = qrow[2][0], nx3 = qrow[3][0];
        for (int k = 0; k < 16; k++) {
            float4 x0 = nx0, x1 = nx1, x2 = nx2, x3 = nx3;
            if (k < 15) {
                nx0 = qrow[0][k + 1]; nx1 = qrow[1][k + 1];
                nx2 = qrow[2][k + 1]; nx3 = qrow[3][k + 1];
            }
            const float* r0 = &rl[(4 * k + 0) * 32 + hh * 16];
            const float* r1 = &rl[(4 * k + 1) * 32 + hh * 16];
            const float* r2 = &rl[(4 * k + 2) * 32 + hh * 16];
            const float* r3 = &rl[(4 * k + 3) * 32 + hh * 16];
            #pragma unroll
            for (int i = 0; i < 16; i++) {
                float a0 = r0[i], a1 = r1[i], a2 = r2[i], a3 = r3[i];
                acc[0][i] += x0.x * a0 + x0.y * a1 + x0.z * a2 + x0.w * a3;
                acc[1][i] += x1.x * a0 + x1.y * a1 + x1.z * a2 + x1.w * a3;
                acc[2][i] += x2.x * a0 + x2.y * a1 + x2.z * a2 + x2.w * a3;
                acc[3][i] += x3.x * a0 + x3.y * a1 + x3.z * a2 + x3.w * a3;
            }
        }

        #pragma unroll
        for (int u = 0; u < 4; u++) {
            #pragma unroll
            for (int i = 0; i < 16; i++) {
                float v = acc[u][i];
                int idx = hh * 16 + i;
                if (v > best[u] || (v == best[u] && idx < bi[u])) { best[u] = v; bi[u] = idx; }
                float nv = -v;
                int nidx = 32 + hh * 16 + i;
                if (nv > best[u] || (nv == best[u] && nidx < bi[u])) { best[u] = nv; bi[u] = nidx; }
            }
        }
    }

    #pragma unroll
    for (int u = 0; u < 4; u++)
        bucket[bh * S_ + t0 + 256 * u] = bi[u];
}

// ---------------- K2: per-(b,h) stable counting sort ----------------
__global__ void sort_kernel(const int* __restrict__ bucket,
                            int* __restrict__ st) {
    int bh = blockIdx.x;
    int lane = threadIdx.x;
    __shared__ int bl[S_];
    __shared__ int cnt[64 * 64];
    __shared__ int tot[64];
    __shared__ int start[64];

    const int base = bh * S_;
    for (int k = 0; k < 64; k++) bl[k * 64 + lane] = bucket[base + k * 64 + lane];
    for (int k = 0; k < 64; k++) cnt[k * 64 + lane] = 0;
    __syncthreads();

    {
        int g = lane;
        for (int j = 0; j < 64; j++) cnt[g * 64 + bl[g * 64 + j]]++;
    }
    __syncthreads();
    {
        int bk = lane, s = 0;
        for (int g = 0; g < 64; g++) s += cnt[g * 64 + bk];
        tot[bk] = s;
    }
    __syncthreads();
    if (lane == 0) {
        int run = 0;
        for (int bk = 0; bk < 64; bk++) { start[bk] = run; run += tot[bk]; }
    }
    __syncthreads();
    {
        int bk = lane;
        int run = start[bk];
        for (int g = 0; g < 64; g++) {
            int c = cnt[g * 64 + bk];
            cnt[g * 64 + bk] = run;
            run += c;
        }
    }
    __syncthreads();
    {
        int g = lane;
        for (int j = 0; j < 64; j++) {
            int t = g * 64 + j;
            int bk = bl[t];
            int p = cnt[g * 64 + bk]++;
            st[base + p] = t;
        }
    }
}

// ---------------- K3: MFMA chunked attention ----------------
// Block = 1 chunk, 4 waves. S^T = K*Q^T (x32 MFMA, C-layout == x16 A-layout)
// feeds PV from registers. V^T aliases the K region. XCD-aware swizzle:
// contiguous chunk ranges pinned to one XCD so adjacent chunks' shared
// staging rows hit XCD-L2 on reuse.
__global__ void __launch_bounds__(256, 5)
attn_kernel(const float* __restrict__ qk,
            const float* __restrict__ v,
            const int* __restrict__ st,
            unsigned short* __restrict__ ou,   // bf16 (B,H,S,D)
            float* __restrict__ lse_u) {       // (B,H,S)
    const int tid = threadIdx.x;
    const int gid = blockIdx.x;
    const int gc = (gid & 7) * 1024 + (gid >> 3);   // XCD-contiguous global chunk
    const int b = gc >> 9;
    const int cc = gc & 511;
    const int prev = (cc - 1) & 511;
    const int h = cc >> 6;

    __shared__ alignas(16) unsigned short KV[128 * QS_];  // K rows, then V^T
    __shared__ alignas(16) unsigned short Ps[64 * PS_];   // O transpose staging
    __shared__ int tkv[128];
    __shared__ float bounds[64];

    const int stBase = b * (CHUNKS_ * M_);
    if (tid < 128) tkv[tid] = st[stBase + (tid < 64 ? cc : prev) * 64 + (tid & 63)];
    __syncthreads();

    const int stok = tid >> 2;                 // 0..63 (token within pass)
    const int q4 = tid & 3;                    // 16-feature slice

    // ---- stage normalized K; hold V (packed bf16) in regs ----
    unsigned vpk[2][8];
    #pragma unroll
    for (int p = 0; p < 2; p++) {
        int tok = p * 64 + stok;
        int pos = tkv[tok];
        const float4* src = (const float4*)(qk + (size_t)(b * S_ + pos) * 64) + q4 * 4;
        float4 x0 = src[0], x1 = src[1], x2 = src[2], x3 = src[3];
        const float4* vsrc = (const float4*)(v + (size_t)(b * S_ + pos) * 64) + q4 * 4;
        float4 y0 = vsrc[0], y1 = vsrc[1], y2 = vsrc[2], y3 = vsrc[3];

        float ss = x0.x*x0.x + x0.y*x0.y + x0.z*x0.z + x0.w*x0.w
                 + x1.x*x1.x + x1.y*x1.y + x1.z*x1.z + x1.w*x1.w
                 + x2.x*x2.x + x2.y*x2.y + x2.z*x2.z + x2.w*x2.w
                 + x3.x*x3.x + x3.y*x3.y + x3.z*x3.z + x3.w*x3.w;
        ss += __shfl_xor(ss, 1);
        ss += __shfl_xor(ss, 2);
        float nrm = sqrtf(ss);
        float rn = 1.f / fmaxf(nrm, 1e-12f);

        float4 k0 = make_float4(x0.x*rn, x0.y*rn, x0.z*rn, x0.w*rn);
        float4 k1 = make_float4(x1.x*rn, x1.y*rn, x1.z*rn, x1.w*rn);
        float4 k2 = make_float4(x2.x*rn, x2.y*rn, x2.z*rn, x2.w*rn);
        float4 k3 = make_float4(x3.x*rn, x3.y*rn, x3.z*rn, x3.w*rn);
        *(uint4*)&KV[tok * QS_ + q4 * 16]     = pack8(k0, k1);
        *(uint4*)&KV[tok * QS_ + q4 * 16 + 8] = pack8(k2, k3);

        vpk[p][0] = pk2(y0.x, y0.y); vpk[p][1] = pk2(y0.z, y0.w);
        vpk[p][2] = pk2(y1.x, y1.y); vpk[p][3] = pk2(y1.z, y1.w);
        vpk[p][4] = pk2(y2.x, y2.y); vpk[p][5] = pk2(y2.z, y2.w);
        vpk[p][6] = pk2(y3.x, y3.y); vpk[p][7] = pk2(y3.z, y3.w);

        if (p == 0 && q4 == 0) bounds[tok] = nrm * 0.125f;
    }
    __syncthreads();

    const int lane = tid & 63;
    const int w = tid >> 6;
    const int lm = lane & 15;
    const int lq = lane >> 4;

    // ---- per-lane q scalars (col = lm) ----
    const int   tq  = tkv[w * 16 + lm];
    const float bnd = bounds[w * 16 + lm];
    const float bl2 = bnd * LOG2E;

    // ---- S^T = K * Q^T (A = kv rows, B = q rows of wave w) ----
    const short8 bq0 = *(const short8*)&KV[(w * 16 + lm) * QS_ + lq * 8];
    const short8 bq1 = *(const short8*)&KV[(w * 16 + lm) * QS_ + 32 + lq * 8];
    floatx4 C[8];
    #pragma unroll
    for (int nt = 0; nt < 8; nt++) {
        const short8 a0 = *(const short8*)&KV[(nt * 16 + lm) * QS_ + lq * 8];
        const short8 a1 = *(const short8*)&KV[(nt * 16 + lm) * QS_ + 32 + lq * 8];
        floatx4 c = {0.f, 0.f, 0.f, 0.f};
        c = __builtin_amdgcn_mfma_f32_16x16x32_bf16(a0, bq0, c, 0, 0, 0);
        c = __builtin_amdgcn_mfma_f32_16x16x32_bf16(a1, bq1, c, 0, 0, 0);
        C[nt] = c;
    }

    // ---- mask + exp (bound trick) -> P kept in registers as x16 A-frags ----
    float lsum = 0.f, ns = 0.f;
    short4v pa[8];
    #pragma unroll
    for (int nt = 0; nt < 8; nt++) {
        int4 tki = *(const int4*)&tkv[nt * 16 + lq * 4];   // kv pos, r=0..3
        float p0 = (tki.x < tq) ? exp2f((C[nt][0] - 1.f) * bl2) : 0.f;
        float p1 = (tki.y < tq) ? exp2f((C[nt][1] - 1.f) * bl2) : 0.f;
        float p2 = (tki.z < tq) ? exp2f((C[nt][2] - 1.f) * bl2) : 0.f;
        float p3 = (tki.w < tq) ? exp2f((C[nt][3] - 1.f) * bl2) : 0.f;
        ns += (tki.x == tq) ? 1.f : 0.f;
        ns += (tki.y == tq) ? 1.f : 0.f;
        ns += (tki.z == tq) ? 1.f : 0.f;
        ns += (tki.w == tq) ? 1.f : 0.f;
        lsum += (p0 + p1) + (p2 + p3);
        pa[nt] = mk4(pk2(p0, p1), pk2(p2, p3));
    }
    lsum += __shfl_xor(lsum, 16);
    lsum += __shfl_xor(lsum, 32);
    ns   += __shfl_xor(ns, 16);
    ns   += __shfl_xor(ns, 32);
    __syncthreads();   // all waves done reading K region

    // ---- restage V^T over K region (dword = token pair, XOR-q4 swizzle) ----
    {
        unsigned* VT = (unsigned*)KV;
        const int par = stok & 1;
        #pragma unroll
        for (int p = 0; p < 2; p++) {
            int pd = p * 32 + (stok >> 1);
            int pdw = pd ^ (q4 << 3);
            #pragma unroll
            for (int i = 0; i < 8; i++) {
                unsigned mine = vpk[p][i];
                unsigned theirs = (unsigned)__shfl_xor((int)mine, 4);
                unsigned outw = par ? ((theirs >> 16) | (mine & 0xFFFF0000u))
                                    : ((mine & 0xFFFFu) | (theirs << 16));
                VT[(q4 * 16 + 2 * i + par) * VTS_ + pdw] = outw;
            }
        }
    }
    __syncthreads();

    // ---- PV: O[q][feat] via 16x16x16, A = pa (registers), B = V^T b64 reads ----
    const unsigned* VT = (const unsigned*)KV;
    floatx4 O[4];
    #pragma unroll
    for (int nt2 = 0; nt2 < 4; nt2++) O[nt2] = floatx4{0.f, 0.f, 0.f, 0.f};
    #pragma unroll
    for (int kt = 0; kt < 8; kt++) {
        #pragma unroll
        for (int nt2 = 0; nt2 < 4; nt2++) {
            const short4v vb = *(const short4v*)&VT[(nt2 * 16 + lm) * VTS_
                                + ((kt ^ nt2) * 8 + lq * 2)];
            O[nt2] = __builtin_amdgcn_mfma_f32_16x16x16bf16_1k(pa[kt], vb, O[nt2], 0, 0, 0);
        }
    }

    // ---- epilogue ----
    const size_t oBaseBH = (size_t)(b * H_ + h) * S_;
    #pragma unroll
    for (int r = 0; r < 4; r++) {
        int qrow = w * 16 + lq * 4 + r;
        int pos = tkv[qrow];
        float s = __shfl(lsum, lq * 4 + r);
        float invl;
        if (s > 0.f) {
            invl = 1.f / s;
        } else {
            invl = 1.f;
            #pragma unroll
            for (int nt2 = 0; nt2 < 4; nt2++)
                O[nt2][r] = v[(size_t)(b * S_ + pos) * 64 + nt2 * 16 + lm];
        }
        #pragma unroll
        for (int nt2 = 0; nt2 < 4; nt2++)
            Ps[qrow * PS_ + nt2 * 16 + lm] = f2bf1(O[nt2][r] * invl);
    }
    if (lq == 0) {
        float lse = (lsum > 0.f) ? (bnd + log2f(lsum) * LN2)
                                 : (-50000.f + logf(ns));
        lse_u[oBaseBH + tq] = lse;
    }
    {
        int rrow = lane >> 2;
        int seg = lane & 3;
        int qrow = w * 16 + rrow;
        int pos = tkv[qrow];
        uint4 u0 = *(uint4*)&Ps[qrow * PS_ + seg * 16];
        uint4 u1 = *(uint4*)&Ps[qrow * PS_ + seg * 16 + 8];
        unsigned short* dst = ou + (oBaseBH + pos) * 64 + seg * 16;
        *(uint4*)dst = u0;
        *(uint4*)(dst + 8) = u1;
    }
}

// ---------------- K4: combine hash rounds (float4 per thread) ----------------
__global__ void combine_kernel(const unsigned short* __restrict__ ou,
                               const float* __restrict__ lse_u,
                               float* __restrict__ out) {
    int idx = blockIdx.x * 256 + threadIdx.x;   // (b, t, f4): 16 quads per token
    int f4 = idx & 15;
    int t = (idx >> 4) & (S_ - 1);
    int b = idx >> 16;

    const float* lp = lse_u + (size_t)b * (H_ * S_) + t;
    float le[H_];
    float m = -3.4e38f;
    #pragma unroll
    for (int h = 0; h < H_; h++) {
        le[h] = lp[h * S_];
        m = fmaxf(m, le[h]);
    }
    float s = 0.f, e[H_];
    #pragma unroll
    for (int h = 0; h < H_; h++) {
        e[h] = exp2f((le[h] - m) * LOG2E);
        s += e[h];
    }
    float4 o = make_float4(0.f, 0.f, 0.f, 0.f);
    #pragma unroll
    for (int h = 0; h < H_; h++) {
        uint2 u = *(const uint2*)(ou + ((size_t)((b * H_ + h) * S_ + t)) * 64 + f4 * 4);
        o.x += e[h] * bf2f((unsigned short)(u.x & 0xFFFFu));
        o.y += e[h] * bf2f((unsigned short)(u.x >> 16));
        o.z += e[h] * bf2f((unsigned short)(u.y & 0xFFFFu));
        o.w += e[h] * bf2f((unsigned short)(u.y >> 16));
    }
    float inv = 1.f / s;
    ((float4*)out)[idx] = make_float4(o.x * inv, o.y * inv, o.z * inv, o.w * inv);
}

extern "C" void kernel_launch(void* const* d_in, const int* in_sizes, int n_in,
                              void* d_out, int out_size, void* d_ws, size_t ws_size,
                              hipStream_t stream) {
    const float* qk  = (const float*)d_in[0];
    const float* v   = (const float*)d_in[1];
    const float* rot = (const float*)d_in[2];
    float* out = (float*)d_out;

    char* ws = (char*)d_ws;
    int* bucket  = (int*)(ws);
    int* st      = (int*)(ws + 2097152);
    float* lse_u = (float*)(ws + 4194304);
    unsigned short* ou = (unsigned short*)(ws + 6291456);   // bf16, 67 MB

    hash_kernel<<<dim3(B_ * H_ * (S_ / 1024)), dim3(256), 0, stream>>>(qk, rot, bucket);
    sort_kernel<<<dim3(B_ * H_), dim3(64), 0, stream>>>(bucket, st);
    attn_kernel<<<dim3(B_ * CHUNKS_), dim3(256), 0, stream>>>(qk, v, st, ou, lse_u);
    combine_kernel<<<dim3((B_ * S_ * 16) / 256), dim3(256), 0, stream>>>(ou, lse_u, out);
}

// Round 8
// 213.278 us; speedup vs baseline: 1.1347x; 1.1347x over previous
//
#include <hip/hip_runtime.h>
#include <hip/hip_bf16.h>

#define B_ 16
#define S_ 4096
#define D_ 64
#define H_ 8
#define NB_ 64          // n_buckets
#define M_ 64           // bucket_size
#define CHUNKS_ 512     // per batch = H_*NB_
#define LOG2E 1.4426950408889634f
#define LN2 0.6931471805599453f

#define QS_ 72          // K LDS row stride (shorts)
#define VTS_ 68         // V^T row stride (dwords)
#define PS_ 72          // O-transpose staging row stride (shorts)

typedef short short8 __attribute__((ext_vector_type(8)));
typedef short short4v __attribute__((ext_vector_type(4)));
typedef float floatx4 __attribute__((ext_vector_type(4)));

__device__ __forceinline__ float bf2f(unsigned short s) {
    return __uint_as_float(((unsigned int)s) << 16);
}
__device__ __forceinline__ unsigned pk2(float a, float b) {
    __hip_bfloat162 h = __float22bfloat162_rn(make_float2(a, b));
    return *(unsigned*)&h;
}
__device__ __forceinline__ unsigned short f2bf1(float x) {
    return (unsigned short)pk2(x, x);
}
__device__ __forceinline__ uint4 pack8(float4 a, float4 b) {
    uint4 u;
    u.x = pk2(a.x, a.y); u.y = pk2(a.z, a.w);
    u.z = pk2(b.x, b.y); u.w = pk2(b.z, b.w);
    return u;
}
__device__ __forceinline__ short4v mk4(unsigned lo, unsigned hi) {
    uint2 t = make_uint2(lo, hi);
    return *(short4v*)&t;
}

// ---------------- K1: hashing (round-6 version, FROZEN FP ORDER) ----------------
// 2 tokens/thread: best occupancy/DS trade (4 waves/SIMD; 4-tok collapses to
// 2 waves/SIMD and went latency-bound in round 7).
__global__ void __launch_bounds__(256)
hash_kernel(const float* __restrict__ qk,
            const float* __restrict__ rot,
            int* __restrict__ bucket) {
    int bh = blockIdx.x >> 3;      // (b*H + h)
    int tc = blockIdx.x & 7;       // 512-token chunk
    int h = bh & 7;
    int b = bh >> 3;

    __shared__ float rl[64 * 32];
    #pragma unroll
    for (int k = 0; k < 8; k++) {
        int e = k * 256 + threadIdx.x;
        rl[e] = rot[(e >> 5) * (H_ * 32) + h * 32 + (e & 31)];
    }
    __syncthreads();

    const int t0 = tc * 512 + threadIdx.x;   // tokens t0, t0+256

    const float4* qrow0 = (const float4*)(qk + ((size_t)(b * S_ + t0)) * D_);
    const float4* qrow1 = (const float4*)(qk + ((size_t)(b * S_ + t0 + 256)) * D_);

    float acc[2][32];
    #pragma unroll
    for (int u = 0; u < 2; u++)
        #pragma unroll
        for (int i = 0; i < 32; i++) acc[u][i] = 0.f;

    for (int k = 0; k < 16; k++) {
        float4 x0 = qrow0[k];
        float4 x1 = qrow1[k];
        const float* r0 = &rl[(4 * k + 0) * 32];
        const float* r1 = &rl[(4 * k + 1) * 32];
        const float* r2 = &rl[(4 * k + 2) * 32];
        const float* r3 = &rl[(4 * k + 3) * 32];
        #pragma unroll
        for (int i = 0; i < 32; i++) {
            float a0 = r0[i], a1 = r1[i], a2 = r2[i], a3 = r3[i];
            acc[0][i] += x0.x * a0 + x0.y * a1 + x0.z * a2 + x0.w * a3;
            acc[1][i] += x1.x * a0 + x1.y * a1 + x1.z * a2 + x1.w * a3;
        }
    }

    #pragma unroll
    for (int u = 0; u < 2; u++) {
        float best = acc[u][0];
        int bi = 0;
        #pragma unroll
        for (int i = 1; i < 32; i++)
            if (acc[u][i] > best) { best = acc[u][i]; bi = i; }
        #pragma unroll
        for (int i = 0; i < 32; i++) {
            float nv = -acc[u][i];
            if (nv > best) { best = nv; bi = 32 + i; }
        }
        bucket[bh * S_ + t0 + 256 * u] = bi;
    }
}

// ---------------- K2: parallel stable counting sort ----------------
// 256 threads (4 waves) per (b,h). Thread t owns tokens [t*16, t*16+16) as
// one "group"; groups are in position order, so bucket-major-then-group
// prefix + in-group position order == stable sort by (bucket, position).
__global__ void __launch_bounds__(256)
sort_kernel(const int* __restrict__ bucket,
            int* __restrict__ st) {
    const int bh = blockIdx.x;
    const int t = threadIdx.x;
    __shared__ int bl[S_];             // 16 KB
    __shared__ int cnt[256 * 64];      // 64 KB: cnt[group*64 + bucket]
    __shared__ int qsum[64 * 4];       // per-bucket quarter sums
    __shared__ int tot[64];
    __shared__ int start[64];

    const int base = bh * S_;
    #pragma unroll
    for (int i = 0; i < 16; i++) bl[i * 256 + t] = bucket[base + i * 256 + t];
    #pragma unroll
    for (int i = 0; i < 64; i++) cnt[t * 64 + i] = 0;
    __syncthreads();

    // A: per-group histogram (serial 16)
    #pragma unroll
    for (int j = 0; j < 16; j++) cnt[t * 64 + bl[t * 16 + j]]++;
    __syncthreads();

    // B1: quarter sums: thread (bk = t&63, q = t>>6) sums 64 groups
    {
        const int bk = t & 63, q = t >> 6;
        int s = 0;
        for (int g = q * 64; g < q * 64 + 64; g++) s += cnt[g * 64 + bk];
        qsum[bk * 4 + q] = s;
    }
    __syncthreads();

    // B2: bucket totals + global starts
    if (t < 64) tot[t] = qsum[t * 4] + qsum[t * 4 + 1] + qsum[t * 4 + 2] + qsum[t * 4 + 3];
    __syncthreads();
    if (t == 0) {
        int run = 0;
        for (int bk = 0; bk < 64; bk++) { start[bk] = run; run += tot[bk]; }
    }
    __syncthreads();

    // B3: convert cnt to exclusive running prefix (bucket-major, group-minor)
    {
        const int bk = t & 63, q = t >> 6;
        int run = start[bk];
        for (int qq = 0; qq < 4; qq++) if (qq < q) run += qsum[bk * 4 + qq];
        for (int g = q * 64; g < q * 64 + 64; g++) {
            int c = cnt[g * 64 + bk];
            cnt[g * 64 + bk] = run;
            run += c;
        }
    }
    __syncthreads();

    // C: stable placement (serial 16, in position order)
    #pragma unroll
    for (int j = 0; j < 16; j++) {
        int tok = t * 16 + j;
        int bk = bl[tok];
        int p = cnt[t * 64 + bk]++;
        st[base + p] = tok;
    }
}

// ---------------- K3: MFMA chunked attention ----------------
__global__ void __launch_bounds__(256, 5)
attn_kernel(const float* __restrict__ qk,
            const float* __restrict__ v,
            const int* __restrict__ st,
            unsigned short* __restrict__ ou,   // bf16 (B,H,S,D)
            float* __restrict__ lse_u) {       // (B,H,S)
    const int tid = threadIdx.x;
    const int gid = blockIdx.x;
    const int gc = (gid & 7) * 1024 + (gid >> 3);   // XCD-contiguous global chunk
    const int b = gc >> 9;
    const int cc = gc & 511;
    const int prev = (cc - 1) & 511;
    const int h = cc >> 6;

    __shared__ alignas(16) unsigned short KV[128 * QS_];  // K rows, then V^T
    __shared__ alignas(16) unsigned short Ps[64 * PS_];   // O transpose staging
    __shared__ int tkv[128];
    __shared__ float bounds[64];

    const int stBase = b * (CHUNKS_ * M_);
    if (tid < 128) tkv[tid] = st[stBase + (tid < 64 ? cc : prev) * 64 + (tid & 63)];
    __syncthreads();

    const int stok = tid >> 2;                 // 0..63 (token within pass)
    const int q4 = tid & 3;                    // 16-feature slice

    // ---- stage normalized K; hold V (packed bf16) in regs ----
    unsigned vpk[2][8];
    #pragma unroll
    for (int p = 0; p < 2; p++) {
        int tok = p * 64 + stok;
        int pos = tkv[tok];
        const float4* src = (const float4*)(qk + (size_t)(b * S_ + pos) * 64) + q4 * 4;
        float4 x0 = src[0], x1 = src[1], x2 = src[2], x3 = src[3];
        const float4* vsrc = (const float4*)(v + (size_t)(b * S_ + pos) * 64) + q4 * 4;
        float4 y0 = vsrc[0], y1 = vsrc[1], y2 = vsrc[2], y3 = vsrc[3];

        float ss = x0.x*x0.x + x0.y*x0.y + x0.z*x0.z + x0.w*x0.w
                 + x1.x*x1.x + x1.y*x1.y + x1.z*x1.z + x1.w*x1.w
                 + x2.x*x2.x + x2.y*x2.y + x2.z*x2.z + x2.w*x2.w
                 + x3.x*x3.x + x3.y*x3.y + x3.z*x3.z + x3.w*x3.w;
        ss += __shfl_xor(ss, 1);
        ss += __shfl_xor(ss, 2);
        float nrm = sqrtf(ss);
        float rn = 1.f / fmaxf(nrm, 1e-12f);

        float4 k0 = make_float4(x0.x*rn, x0.y*rn, x0.z*rn, x0.w*rn);
        float4 k1 = make_float4(x1.x*rn, x1.y*rn, x1.z*rn, x1.w*rn);
        float4 k2 = make_float4(x2.x*rn, x2.y*rn, x2.z*rn, x2.w*rn);
        float4 k3 = make_float4(x3.x*rn, x3.y*rn, x3.z*rn, x3.w*rn);
        *(uint4*)&KV[tok * QS_ + q4 * 16]     = pack8(k0, k1);
        *(uint4*)&KV[tok * QS_ + q4 * 16 + 8] = pack8(k2, k3);

        vpk[p][0] = pk2(y0.x, y0.y); vpk[p][1] = pk2(y0.z, y0.w);
        vpk[p][2] = pk2(y1.x, y1.y); vpk[p][3] = pk2(y1.z, y1.w);
        vpk[p][4] = pk2(y2.x, y2.y); vpk[p][5] = pk2(y2.z, y2.w);
        vpk[p][6] = pk2(y3.x, y3.y); vpk[p][7] = pk2(y3.z, y3.w);

        if (p == 0 && q4 == 0) bounds[tok] = nrm * 0.125f;
    }
    __syncthreads();

    const int lane = tid & 63;
    const int w = tid >> 6;
    const int lm = lane & 15;
    const int lq = lane >> 4;

    const int   tq  = tkv[w * 16 + lm];
    const float bnd = bounds[w * 16 + lm];
    const float bl2 = bnd * LOG2E;

    // ---- S^T = K * Q^T ----
    const short8 bq0 = *(const short8*)&KV[(w * 16 + lm) * QS_ + lq * 8];
    const short8 bq1 = *(const short8*)&KV[(w * 16 + lm) * QS_ + 32 + lq * 8];
    floatx4 C[8];
    #pragma unroll
    for (int nt = 0; nt < 8; nt++) {
        const short8 a0 = *(const short8*)&KV[(nt * 16 + lm) * QS_ + lq * 8];
        const short8 a1 = *(const short8*)&KV[(nt * 16 + lm) * QS_ + 32 + lq * 8];
        floatx4 c = {0.f, 0.f, 0.f, 0.f};
        c = __builtin_amdgcn_mfma_f32_16x16x32_bf16(a0, bq0, c, 0, 0, 0);
        c = __builtin_amdgcn_mfma_f32_16x16x32_bf16(a1, bq1, c, 0, 0, 0);
        C[nt] = c;
    }

    // ---- mask + exp -> P in registers as x16 A-frags ----
    float lsum = 0.f, ns = 0.f;
    short4v pa[8];
    #pragma unroll
    for (int nt = 0; nt < 8; nt++) {
        int4 tki = *(const int4*)&tkv[nt * 16 + lq * 4];
        float p0 = (tki.x < tq) ? exp2f((C[nt][0] - 1.f) * bl2) : 0.f;
        float p1 = (tki.y < tq) ? exp2f((C[nt][1] - 1.f) * bl2) : 0.f;
        float p2 = (tki.z < tq) ? exp2f((C[nt][2] - 1.f) * bl2) : 0.f;
        float p3 = (tki.w < tq) ? exp2f((C[nt][3] - 1.f) * bl2) : 0.f;
        ns += (tki.x == tq) ? 1.f : 0.f;
        ns += (tki.y == tq) ? 1.f : 0.f;
        ns += (tki.z == tq) ? 1.f : 0.f;
        ns += (tki.w == tq) ? 1.f : 0.f;
        lsum += (p0 + p1) + (p2 + p3);
        pa[nt] = mk4(pk2(p0, p1), pk2(p2, p3));
    }
    lsum += __shfl_xor(lsum, 16);
    lsum += __shfl_xor(lsum, 32);
    ns   += __shfl_xor(ns, 16);
    ns   += __shfl_xor(ns, 32);
    __syncthreads();

    // ---- restage V^T over K region ----
    {
        unsigned* VT = (unsigned*)KV;
        const int par = stok & 1;
        #pragma unroll
        for (int p = 0; p < 2; p++) {
            int pd = p * 32 + (stok >> 1);
            int pdw = pd ^ (q4 << 3);
            #pragma unroll
            for (int i = 0; i < 8; i++) {
                unsigned mine = vpk[p][i];
                unsigned theirs = (unsigned)__shfl_xor((int)mine, 4);
                unsigned outw = par ? ((theirs >> 16) | (mine & 0xFFFF0000u))
                                    : ((mine & 0xFFFFu) | (theirs << 16));
                VT[(q4 * 16 + 2 * i + par) * VTS_ + pdw] = outw;
            }
        }
    }
    __syncthreads();

    // ---- PV ----
    const unsigned* VT = (const unsigned*)KV;
    floatx4 O[4];
    #pragma unroll
    for (int nt2 = 0; nt2 < 4; nt2++) O[nt2] = floatx4{0.f, 0.f, 0.f, 0.f};
    #pragma unroll
    for (int kt = 0; kt < 8; kt++) {
        #pragma unroll
        for (int nt2 = 0; nt2 < 4; nt2++) {
            const short4v vb = *(const short4v*)&VT[(nt2 * 16 + lm) * VTS_
                                + ((kt ^ nt2) * 8 + lq * 2)];
            O[nt2] = __builtin_amdgcn_mfma_f32_16x16x16bf16_1k(pa[kt], vb, O[nt2], 0, 0, 0);
        }
    }

    // ---- epilogue ----
    const size_t oBaseBH = (size_t)(b * H_ + h) * S_;
    #pragma unroll
    for (int r = 0; r < 4; r++) {
        int qrow = w * 16 + lq * 4 + r;
        int pos = tkv[qrow];
        float s = __shfl(lsum, lq * 4 + r);
        float invl;
        if (s > 0.f) {
            invl = 1.f / s;
        } else {
            invl = 1.f;
            #pragma unroll
            for (int nt2 = 0; nt2 < 4; nt2++)
                O[nt2][r] = v[(size_t)(b * S_ + pos) * 64 + nt2 * 16 + lm];
        }
        #pragma unroll
        for (int nt2 = 0; nt2 < 4; nt2++)
            Ps[qrow * PS_ + nt2 * 16 + lm] = f2bf1(O[nt2][r] * invl);
    }
    if (lq == 0) {
        float lse = (lsum > 0.f) ? (bnd + log2f(lsum) * LN2)
                                 : (-50000.f + logf(ns));
        lse_u[oBaseBH + tq] = lse;
    }
    {
        int rrow = lane >> 2;
        int seg = lane & 3;
        int qrow = w * 16 + rrow;
        int pos = tkv[qrow];
        uint4 u0 = *(uint4*)&Ps[qrow * PS_ + seg * 16];
        uint4 u1 = *(uint4*)&Ps[qrow * PS_ + seg * 16 + 8];
        unsigned short* dst = ou + (oBaseBH + pos) * 64 + seg * 16;
        *(uint4*)dst = u0;
        *(uint4*)(dst + 8) = u1;
    }
}

// ---------------- K4: combine hash rounds (float4 per thread) ----------------
__global__ void combine_kernel(const unsigned short* __restrict__ ou,
                               const float* __restrict__ lse_u,
                               float* __restrict__ out) {
    int idx = blockIdx.x * 256 + threadIdx.x;
    int f4 = idx & 15;
    int t = (idx >> 4) & (S_ - 1);
    int b = idx >> 16;

    const float* lp = lse_u + (size_t)b * (H_ * S_) + t;
    float le[H_];
    float m = -3.4e38f;
    #pragma unroll
    for (int h = 0; h < H_; h++) {
        le[h] = lp[h * S_];
        m = fmaxf(m, le[h]);
    }
    float s = 0.f, e[H_];
    #pragma unroll
    for (int h = 0; h < H_; h++) {
        e[h] = exp2f((le[h] - m) * LOG2E);
        s += e[h];
    }
    float4 o = make_float4(0.f, 0.f, 0.f, 0.f);
    #pragma unroll
    for (int h = 0; h < H_; h++) {
        uint2 u = *(const uint2*)(ou + ((size_t)((b * H_ + h) * S_ + t)) * 64 + f4 * 4);
        o.x += e[h] * bf2f((unsigned short)(u.x & 0xFFFFu));
        o.y += e[h] * bf2f((unsigned short)(u.x >> 16));
        o.z += e[h] * bf2f((unsigned short)(u.y & 0xFFFFu));
        o.w += e[h] * bf2f((unsigned short)(u.y >> 16));
    }
    float inv = 1.f / s;
    ((float4*)out)[idx] = make_float4(o.x * inv, o.y * inv, o.z * inv, o.w * inv);
}

extern "C" void kernel_launch(void* const* d_in, const int* in_sizes, int n_in,
                              void* d_out, int out_size, void* d_ws, size_t ws_size,
                              hipStream_t stream) {
    const float* qk  = (const float*)d_in[0];
    const float* v   = (const float*)d_in[1];
    const float* rot = (const float*)d_in[2];
    float* out = (float*)d_out;

    char* ws = (char*)d_ws;
    int* bucket  = (int*)(ws);
    int* st      = (int*)(ws + 2097152);
    float* lse_u = (float*)(ws + 4194304);
    unsigned short* ou = (unsigned short*)(ws + 6291456);   // bf16, 67 MB

    hash_kernel<<<dim3(B_ * H_ * (S_ / 512)), dim3(256), 0, stream>>>(qk, rot, bucket);
    sort_kernel<<<dim3(B_ * H_), dim3(256), 0, stream>>>(bucket, st);
    attn_kernel<<<dim3(B_ * CHUNKS_), dim3(256), 0, stream>>>(qk, v, st, ou, lse_u);
    combine_kernel<<<dim3((B_ * S_ * 16) / 256), dim3(256), 0, stream>>>(ou, lse_u, out);
}